// Round 1
// baseline (192.462 us; speedup 1.0000x reference)
//
#include <hip/hip_runtime.h>

// HeightmapNormalsLoss: fused Sobel-normals + L1 mean over two [32,1,512,512] fp32 images.
// Memory-bound: 67 MB read, 1 float out. Single kernel, LDS-tiled stencil, global atomic reduce.

#define IMG_H 512
#define IMG_W 512
#define TW 128          // tile width  (output pixels)
#define TH 8            // tile height (output pixels)
#define PW (TW + 2)     // padded tile width  = 130
#define PH (TH + 2)     // padded tile height = 10
#define NTHREADS 256

__device__ __forceinline__ float3 sobel_normal(const float s[PH][PW], int r, int c) {
    float a = s[r-1][c-1], b = s[r-1][c], cc = s[r-1][c+1];
    float d = s[r  ][c-1],                e  = s[r  ][c+1];
    float f = s[r+1][c-1], g = s[r+1][c], h  = s[r+1][c+1];
    // cross-correlation with SOBEL_X = [[1,0,-1],[2,0,-2],[1,0,-1]]
    float gx = (a + 2.f*d + f) - (cc + 2.f*e + h);
    // SOBEL_Y = [[1,2,1],[0,0,0],[-1,-2,-1]]
    float gy = (a + 2.f*b + cc) - (f + 2.f*g + h);
    float gz = 0.25f * sqrtf(1.f - gx*gx - gy*gy);
    float invlen = rsqrtf(4.f*(gx*gx + gy*gy) + gz*gz);
    return make_float3(gx * invlen, gy * invlen, gz * invlen);
}

__global__ __launch_bounds__(NTHREADS)
void heightmap_normals_loss_kernel(const float* __restrict__ gen,
                                   const float* __restrict__ tgt,
                                   float* __restrict__ out,
                                   float inv_count) {
    __shared__ float sg[PH][PW];
    __shared__ float st[PH][PW];

    const int b  = blockIdx.z;
    const int h0 = blockIdx.y * TH;
    const int w0 = blockIdx.x * TW;
    const int t  = threadIdx.x;

    const float* __restrict__ gbase = gen + (size_t)b * (IMG_H * IMG_W);
    const float* __restrict__ tbase = tgt + (size_t)b * (IMG_H * IMG_W);

    // Cooperative load of padded tile with edge clamping (ReplicationPad2d(1)).
    #pragma unroll
    for (int idx = t; idx < PH * PW; idx += NTHREADS) {
        int r = idx / PW;
        int c = idx - r * PW;
        int gh = h0 - 1 + r; gh = max(0, min(IMG_H - 1, gh));
        int gw = w0 - 1 + c; gw = max(0, min(IMG_W - 1, gw));
        size_t off = (size_t)gh * IMG_W + gw;
        sg[r][c] = gbase[off];
        st[r][c] = tbase[off];
    }
    __syncthreads();

    const int tx = t & (TW - 1);   // 0..127
    const int ty = t >> 7;         // 0..1

    float acc = 0.f;
    #pragma unroll
    for (int hh = 0; hh < TH / 2; ++hh) {
        int r = 1 + ty + hh * 2;
        int c = 1 + tx;
        float3 ng = sobel_normal(sg, r, c);
        float3 nt = sobel_normal(st, r, c);
        acc += fabsf(ng.x - nt.x) + fabsf(ng.y - nt.y) + fabsf(ng.z - nt.z);
    }

    // Wave-64 butterfly reduce.
    #pragma unroll
    for (int o = 32; o > 0; o >>= 1)
        acc += __shfl_xor(acc, o, 64);

    __shared__ float wsum[NTHREADS / 64];
    const int wave = t >> 6;
    const int lane = t & 63;
    if (lane == 0) wsum[wave] = acc;
    __syncthreads();
    if (t == 0) {
        float s = 0.f;
        #pragma unroll
        for (int w = 0; w < NTHREADS / 64; ++w) s += wsum[w];
        atomicAdd(out, s * inv_count);
    }
}

extern "C" void kernel_launch(void* const* d_in, const int* in_sizes, int n_in,
                              void* d_out, int out_size, void* d_ws, size_t ws_size,
                              hipStream_t stream) {
    const float* gen = (const float*)d_in[0];
    const float* tgt = (const float*)d_in[1];
    float* out = (float*)d_out;

    const int B = in_sizes[0] / (IMG_H * IMG_W);   // 32
    const float inv_count = 1.f / ((float)B * 3.f * IMG_H * IMG_W);

    // d_out is poisoned to 0xAA before every timed launch — zero it first.
    hipMemsetAsync(out, 0, sizeof(float), stream);

    dim3 grid(IMG_W / TW, IMG_H / TH, B);   // (4, 64, 32) = 8192 blocks
    dim3 block(NTHREADS);
    heightmap_normals_loss_kernel<<<grid, block, 0, stream>>>(gen, tgt, out, inv_count);
}

// Round 2
// 159.479 us; speedup vs baseline: 1.2068x; 1.2068x over previous
//
#include <hip/hip_runtime.h>

// HeightmapNormalsLoss: fused Sobel-normals + L1 mean over two [32,1,512,512] fp32 images.
// R2: barrier-free rolling-register stencil. float4 loads, shfl horizontal halos,
// per-block partials to d_ws + tiny reduce kernel (kills the 8192-way same-address atomic).

#define IMG_H 512
#define IMG_W 512
#define RPW   8          // output rows per wave
#define BAND  32         // rows per block = 4 row-subwaves * RPW
#define NT    512        // threads per block = 8 waves: 2 column halves x 4 row subbands

// Compute the 4 Sobel normals (nx,ny,nz interleaved) for this lane's 4 columns,
// given rows p (r-1), c (r), n (r+1) as float4 + the lane-edge halo scalars.
__device__ __forceinline__ void normals4(float4 p, float ph, float4 c, float ch,
                                         float4 n, float nh,
                                         int lane, int colHalf, float out[12]) {
    // horizontal neighbors across lanes
    float pL = __shfl_up(p.w, 1, 64), pR = __shfl_down(p.x, 1, 64);
    float cL = __shfl_up(c.w, 1, 64), cR = __shfl_down(c.x, 1, 64);
    float nL = __shfl_up(n.w, 1, 64), nR = __shfl_down(n.x, 1, 64);
    if (lane == 0)  {   // left edge of wave: image edge-clamp (colHalf 0) or cross-wave halo (colHalf 1)
        pL = (colHalf == 0) ? p.x : ph;
        cL = (colHalf == 0) ? c.x : ch;
        nL = (colHalf == 0) ? n.x : nh;
    }
    if (lane == 63) {   // right edge of wave
        pR = (colHalf == 1) ? p.w : ph;
        cR = (colHalf == 1) ? c.w : ch;
        nR = (colHalf == 1) ? n.w : nh;
    }

    float ep[6] = {pL, p.x, p.y, p.z, p.w, pR};
    float ec[6] = {cL, c.x, c.y, c.z, c.w, cR};
    float en[6] = {nL, n.x, n.y, n.z, n.w, nR};
    float sv[6], sh[6];
    #pragma unroll
    for (int k = 0; k < 6; ++k) {
        sv[k] = ep[k] + 2.f * ec[k] + en[k];   // vertical [1,2,1] for gx
        sh[k] = ep[k] - en[k];                 // vertical [1,0,-1] for gy
    }
    #pragma unroll
    for (int j = 0; j < 4; ++j) {
        float gx = sv[j] - sv[j + 2];                      // horizontal [1,0,-1]
        float gy = sh[j] + 2.f * sh[j + 1] + sh[j + 2];    // horizontal [1,2,1]
        float q  = gx * gx + gy * gy;
        float gz = 0.25f * sqrtf(1.f - q);
        float inv = rsqrtf(4.f * q + gz * gz);
        out[j * 3 + 0] = gx * inv;
        out[j * 3 + 1] = gy * inv;
        out[j * 3 + 2] = gz * inv;
    }
}

__global__ __launch_bounds__(NT, 4)
void hnl_main(const float* __restrict__ gen, const float* __restrict__ tgt,
              float* __restrict__ partial) {
    const int t    = threadIdx.x;
    const int wave = t >> 6;
    const int lane = t & 63;
    const int colHalf = wave & 1;        // 0: cols 0..255, 1: cols 256..511
    const int rowSub  = wave >> 1;       // 0..3
    const int img  = blockIdx.y;
    const int band = blockIdx.x;
    const int rbase = band * BAND + rowSub * RPW;
    const int c0 = colHalf * 256 + lane * 4;

    const size_t ib = (size_t)img * (IMG_H * IMG_W);
    const float* gp = gen + ib;
    const float* tp = tgt + ib;

    const bool haloL = (lane == 0)  && (colHalf == 1);   // needs col 255
    const bool haloR = (lane == 63) && (colHalf == 0);   // needs col 256
    const bool needHalo = haloL || haloR;
    const int  haloCol = haloL ? 255 : 256;

    auto ldrow = [&](const float* base, int r, float4& v, float& hal) {
        int rc = min(IMG_H - 1, max(0, r));              // ReplicationPad2d vertical clamp
        const float* rowp = base + (size_t)rc * IMG_W;
        v = *reinterpret_cast<const float4*>(rowp + c0);
        hal = needHalo ? rowp[haloCol] : 0.f;
    };

    float4 gP, gC, gN, tP, tC, tN;
    float  gPh, gCh, gNh, tPh, tCh, tNh;
    ldrow(gp, rbase - 1, gP, gPh); ldrow(gp, rbase, gC, gCh);
    ldrow(tp, rbase - 1, tP, tPh); ldrow(tp, rbase, tC, tCh);

    float acc = 0.f;
    #pragma unroll
    for (int i = 0; i < RPW; ++i) {
        ldrow(gp, rbase + i + 1, gN, gNh);
        ldrow(tp, rbase + i + 1, tN, tNh);
        float a[12], b[12];
        normals4(gP, gPh, gC, gCh, gN, gNh, lane, colHalf, a);
        normals4(tP, tPh, tC, tCh, tN, tNh, lane, colHalf, b);
        #pragma unroll
        for (int k = 0; k < 12; ++k) acc += fabsf(a[k] - b[k]);
        gP = gC; gPh = gCh; gC = gN; gCh = gNh;
        tP = tC; tPh = tCh; tC = tN; tCh = tNh;
    }

    // wave butterfly + block reduce, one partial per block (no global atomics)
    #pragma unroll
    for (int o = 32; o; o >>= 1) acc += __shfl_xor(acc, o, 64);
    __shared__ float wsum[NT / 64];
    if (lane == 0) wsum[wave] = acc;
    __syncthreads();
    if (t == 0) {
        float s = 0.f;
        #pragma unroll
        for (int w = 0; w < NT / 64; ++w) s += wsum[w];
        partial[blockIdx.y * gridDim.x + blockIdx.x] = s;
    }
}

__global__ __launch_bounds__(256)
void hnl_reduce(const float* __restrict__ partial, float* __restrict__ out,
                int n, float scale) {
    const int t = threadIdx.x;
    float s = 0.f;
    for (int i = t; i < n; i += 256) s += partial[i];
    #pragma unroll
    for (int o = 32; o; o >>= 1) s += __shfl_xor(s, o, 64);
    __shared__ float wsum[4];
    if ((t & 63) == 0) wsum[t >> 6] = s;
    __syncthreads();
    if (t == 0) out[0] = (wsum[0] + wsum[1] + wsum[2] + wsum[3]) * scale;
}

extern "C" void kernel_launch(void* const* d_in, const int* in_sizes, int n_in,
                              void* d_out, int out_size, void* d_ws, size_t ws_size,
                              hipStream_t stream) {
    const float* gen = (const float*)d_in[0];
    const float* tgt = (const float*)d_in[1];
    float* out = (float*)d_out;
    float* ws  = (float*)d_ws;

    const int B = in_sizes[0] / (IMG_H * IMG_W);     // 32
    const int nBands = IMG_H / BAND;                 // 16
    const int nPartials = B * nBands;                // 512
    const float scale = 1.f / ((float)B * 3.f * IMG_H * IMG_W);

    dim3 grid(nBands, B);
    hnl_main<<<grid, NT, 0, stream>>>(gen, tgt, ws);
    hnl_reduce<<<1, 256, 0, stream>>>(ws, out, nPartials, scale);
}

// Round 3
// 109.412 us; speedup vs baseline: 1.7591x; 1.4576x over previous
//
#include <hip/hip_runtime.h>

// HeightmapNormalsLoss: fused Sobel-normals + L1 mean over two [32,1,512,512] fp32 images.
// R3: register-lean separable stencil. Per-row horizontal prefilters (u=[1,0,-1], v=[1,2,1])
// rolled in registers; no arrays, no launch_bounds reg-cap -> no scratch spill.

#define IMG_H 512
#define IMG_W 512
#define RPW   8              // output rows per wave
#define BAND  (2 * RPW)      // 16 rows per block (2 row-subbands)
#define NT    256            // 4 waves: 2 column halves x 2 row subbands

// Horizontal prefilters for one row: u = [1,0,-1] cross-corr, v = [1,2,1].
__device__ __forceinline__ void hfilt(float4 x, float xh, int lane, int colHalf,
                                      float4& u, float4& v) {
    float xm = __shfl_up(x.w, 1, 64);    // left neighbor of this lane's col0
    float xp = __shfl_down(x.x, 1, 64);  // right neighbor of this lane's col3
    if (lane == 0)  xm = (colHalf == 0) ? x.x : xh;   // image edge clamp / cross-wave halo
    if (lane == 63) xp = (colHalf == 1) ? x.w : xh;
    u.x = xm  - x.y;  u.y = x.x - x.z;  u.z = x.y - x.w;  u.w = x.z - xp;
    v.x = xm  + 2.f * x.x + x.y;
    v.y = x.x + 2.f * x.y + x.z;
    v.z = x.y + 2.f * x.z + x.w;
    v.w = x.z + 2.f * x.w + xp;
}

// |n(gen) - n(tgt)| summed over 3 components, for one pixel.
// n = (4gx, 4gy, sqrt(1-q)) * rsqrt(63q+1), q = gx^2+gy^2  (algebraic fold of reference).
__device__ __forceinline__ float pixdiff(float gxa, float gya, float gxb, float gyb) {
    float qa = fmaf(gxa, gxa, gya * gya);
    float qb = fmaf(gxb, gxb, gyb * gyb);
    float ta = rsqrtf(fmaf(63.f, qa, 1.f));
    float tb = rsqrtf(fmaf(63.f, qb, 1.f));
    return fabsf(4.f * gxa * ta - 4.f * gxb * tb)
         + fabsf(4.f * gya * ta - 4.f * gyb * tb)
         + fabsf(sqrtf(1.f - qa) * ta - sqrtf(1.f - qb) * tb);
}

__global__ __launch_bounds__(NT)
void hnl_main(const float* __restrict__ gen, const float* __restrict__ tgt,
              float* __restrict__ partial) {
    const int t    = threadIdx.x;
    const int wave = t >> 6;
    const int lane = t & 63;
    const int colHalf = wave & 1;        // 0: cols 0..255, 1: cols 256..511
    const int rowSub  = wave >> 1;       // 0..1
    const int img  = blockIdx.y;
    const int band = blockIdx.x;
    const int rbase = band * BAND + rowSub * RPW;
    const int c0 = colHalf * 256 + lane * 4;

    const size_t ib = (size_t)img * (IMG_H * IMG_W);
    const float* gp = gen + ib;
    const float* tp = tgt + ib;

    const bool haloL = (lane == 0)  && (colHalf == 1);   // needs col 255
    const bool haloR = (lane == 63) && (colHalf == 0);   // needs col 256
    const bool needHalo = haloL || haloR;
    const int  haloCol = haloL ? 255 : 256;

    auto ldrow = [&](const float* base, int r, float4& x, float& xh) {
        int rc = min(IMG_H - 1, max(0, r));              // ReplicationPad2d vertical clamp
        const float* rp = base + (size_t)rc * IMG_W;
        x  = *reinterpret_cast<const float4*>(rp + c0);
        xh = needHalo ? rp[haloCol] : 0.f;
    };

    float4 x; float xh;
    float4 gup, guc, gvp, gvc, tup, tuc, tvp, tvc;
    ldrow(gp, rbase - 1, x, xh); hfilt(x, xh, lane, colHalf, gup, gvp);
    ldrow(gp, rbase,     x, xh); hfilt(x, xh, lane, colHalf, guc, gvc);
    ldrow(tp, rbase - 1, x, xh); hfilt(x, xh, lane, colHalf, tup, tvp);
    ldrow(tp, rbase,     x, xh); hfilt(x, xh, lane, colHalf, tuc, tvc);

    float acc = 0.f;
    #pragma unroll
    for (int i = 0; i < RPW; ++i) {
        float4 gun, gvn, tun, tvn;
        ldrow(gp, rbase + i + 1, x, xh); hfilt(x, xh, lane, colHalf, gun, gvn);
        ldrow(tp, rbase + i + 1, x, xh); hfilt(x, xh, lane, colHalf, tun, tvn);

        acc += pixdiff(gup.x + 2.f * guc.x + gun.x, gvp.x - gvn.x,
                       tup.x + 2.f * tuc.x + tun.x, tvp.x - tvn.x);
        acc += pixdiff(gup.y + 2.f * guc.y + gun.y, gvp.y - gvn.y,
                       tup.y + 2.f * tuc.y + tun.y, tvp.y - tvn.y);
        acc += pixdiff(gup.z + 2.f * guc.z + gun.z, gvp.z - gvn.z,
                       tup.z + 2.f * tuc.z + tun.z, tvp.z - tvn.z);
        acc += pixdiff(gup.w + 2.f * guc.w + gun.w, gvp.w - gvn.w,
                       tup.w + 2.f * tuc.w + tun.w, tvp.w - tvn.w);

        gup = guc; guc = gun; gvp = gvc; gvc = gvn;
        tup = tuc; tuc = tun; tvp = tvc; tvc = tvn;
    }

    // wave butterfly + block reduce, one partial per block (no global atomics)
    #pragma unroll
    for (int o = 32; o; o >>= 1) acc += __shfl_xor(acc, o, 64);
    __shared__ float wsum[NT / 64];
    if (lane == 0) wsum[wave] = acc;
    __syncthreads();
    if (t == 0) {
        float s = 0.f;
        #pragma unroll
        for (int w = 0; w < NT / 64; ++w) s += wsum[w];
        partial[blockIdx.y * gridDim.x + blockIdx.x] = s;
    }
}

__global__ __launch_bounds__(256)
void hnl_reduce(const float* __restrict__ partial, float* __restrict__ out,
                int n, float scale) {
    const int t = threadIdx.x;
    float s = 0.f;
    for (int i = t; i < n; i += 256) s += partial[i];
    #pragma unroll
    for (int o = 32; o; o >>= 1) s += __shfl_xor(s, o, 64);
    __shared__ float wsum[4];
    if ((t & 63) == 0) wsum[t >> 6] = s;
    __syncthreads();
    if (t == 0) out[0] = (wsum[0] + wsum[1] + wsum[2] + wsum[3]) * scale;
}

extern "C" void kernel_launch(void* const* d_in, const int* in_sizes, int n_in,
                              void* d_out, int out_size, void* d_ws, size_t ws_size,
                              hipStream_t stream) {
    const float* gen = (const float*)d_in[0];
    const float* tgt = (const float*)d_in[1];
    float* out = (float*)d_out;
    float* ws  = (float*)d_ws;

    const int B = in_sizes[0] / (IMG_H * IMG_W);     // 32
    const int nBands = IMG_H / BAND;                 // 32
    const int nPartials = B * nBands;                // 1024
    const float scale = 1.f / ((float)B * 3.f * IMG_H * IMG_W);

    dim3 grid(nBands, B);                            // (32, 32) = 1024 blocks
    hnl_main<<<grid, NT, 0, stream>>>(gen, tgt, ws);
    hnl_reduce<<<1, 256, 0, stream>>>(ws, out, nPartials, scale);
}

// Round 4
// 105.855 us; speedup vs baseline: 1.8182x; 1.0336x over previous
//
#include <hip/hip_runtime.h>

// HeightmapNormalsLoss: fused Sobel-normals + L1 mean over two [32,1,512,512] fp32 images.
// R4: 2-deep software-pipelined rolling-register separable stencil.
// Loads for row i+3 issued at iter i -> ~2 compute iterations of latency cover per load.

#define IMG_H 512
#define IMG_W 512
#define RPW   8              // output rows per wave
#define BAND  (2 * RPW)      // 16 rows per block (2 row-subbands)
#define NT    256            // 4 waves: 2 column halves x 2 row subbands

// Horizontal prefilters for one row: u = [1,0,-1] cross-corr, v = [1,2,1].
__device__ __forceinline__ void hfilt(float4 x, float xh, int lane, int colHalf,
                                      float4& u, float4& v) {
    float xm = __shfl_up(x.w, 1, 64);    // left neighbor of this lane's col0
    float xp = __shfl_down(x.x, 1, 64);  // right neighbor of this lane's col3
    if (lane == 0)  xm = (colHalf == 0) ? x.x : xh;   // image edge clamp / cross-wave halo
    if (lane == 63) xp = (colHalf == 1) ? x.w : xh;
    u.x = xm  - x.y;  u.y = x.x - x.z;  u.z = x.y - x.w;  u.w = x.z - xp;
    v.x = xm  + 2.f * x.x + x.y;
    v.y = x.x + 2.f * x.y + x.z;
    v.z = x.y + 2.f * x.z + x.w;
    v.w = x.z + 2.f * x.w + xp;
}

// |n(gen) - n(tgt)| summed over 3 components for one pixel.
// n = (4gx, 4gy, sqrt(1-q)) * rsqrt(63q+1), q = gx^2+gy^2  (algebraic fold, verified absmax 0.0 in R3).
__device__ __forceinline__ float pixdiff(float gxa, float gya, float gxb, float gyb) {
    float qa = fmaf(gxa, gxa, gya * gya);
    float qb = fmaf(gxb, gxb, gyb * gyb);
    float ta = rsqrtf(fmaf(63.f, qa, 1.f));
    float tb = rsqrtf(fmaf(63.f, qb, 1.f));
    return fabsf(4.f * gxa * ta - 4.f * gxb * tb)
         + fabsf(4.f * gya * ta - 4.f * gyb * tb)
         + fabsf(sqrtf(1.f - qa) * ta - sqrtf(1.f - qb) * tb);
}

__global__ __launch_bounds__(NT)
void hnl_main(const float* __restrict__ gen, const float* __restrict__ tgt,
              float* __restrict__ partial) {
    const int t    = threadIdx.x;
    const int wave = t >> 6;
    const int lane = t & 63;
    const int colHalf = wave & 1;        // 0: cols 0..255, 1: cols 256..511
    const int rowSub  = wave >> 1;       // 0..1
    const int rbase = blockIdx.x * BAND + rowSub * RPW;
    const int c0 = colHalf * 256 + lane * 4;

    const size_t ib = (size_t)blockIdx.y * (IMG_H * IMG_W);
    const float* gp = gen + ib;
    const float* tp = tgt + ib;

    const bool haloL = (lane == 0)  && (colHalf == 1);   // needs col 255
    const bool haloR = (lane == 63) && (colHalf == 0);   // needs col 256
    const bool needHalo = haloL || haloR;
    const int  haloCol = haloL ? 255 : 256;

    auto rowptr = [&](const float* base, int r) {
        int rc = min(IMG_H - 1, max(0, r));              // ReplicationPad2d vertical clamp
        return base + (size_t)rc * IMG_W;
    };
    auto ld = [&](const float* rp, float4& x, float& xh) {
        x  = *reinterpret_cast<const float4*>(rp + c0);
        xh = needHalo ? rp[haloCol] : 0.f;
    };

    // ---- prologue: rows rbase-1 .. rbase+2 ----
    float4 x0g, x0t, x1g, x1t;
    float  h0g, h0t, h1g, h1t;
    ld(rowptr(gp, rbase - 1), x0g, h0g); ld(rowptr(tp, rbase - 1), x0t, h0t);
    ld(rowptr(gp, rbase    ), x1g, h1g); ld(rowptr(tp, rbase    ), x1t, h1t);

    float4 rg, rt;  float rhg, rht;                      // raw row (i+1), ready
    ld(rowptr(gp, rbase + 1), rg, rhg); ld(rowptr(tp, rbase + 1), rt, rht);
    float4 fg, ft;  float fhg, fht;                      // raw row (i+2), in flight
    ld(rowptr(gp, rbase + 2), fg, fhg); ld(rowptr(tp, rbase + 2), ft, fht);

    float4 gup, gvp, guc, gvc, tup, tvp, tuc, tvc;
    hfilt(x0g, h0g, lane, colHalf, gup, gvp); hfilt(x0t, h0t, lane, colHalf, tup, tvp);
    hfilt(x1g, h1g, lane, colHalf, guc, gvc); hfilt(x1t, h1t, lane, colHalf, tuc, tvc);

    float acc = 0.f;
    #pragma unroll
    for (int i = 0; i < RPW; ++i) {
        // issue loads for row rbase+i+3 (consumed at iter i+2)
        float4 ng = fg, nt_ = ft;  float nhg = fhg, nht = fht;
        if (i < RPW - 2) {
            ld(rowptr(gp, rbase + i + 3), ng, nhg);
            ld(rowptr(tp, rbase + i + 3), nt_, nht);
        }

        // filter the ready raw row (rbase+i+1)
        float4 gun, gvn, tun, tvn;
        hfilt(rg, rhg, lane, colHalf, gun, gvn);
        hfilt(rt, rht, lane, colHalf, tun, tvn);

        acc += pixdiff(gup.x + 2.f * guc.x + gun.x, gvp.x - gvn.x,
                       tup.x + 2.f * tuc.x + tun.x, tvp.x - tvn.x);
        acc += pixdiff(gup.y + 2.f * guc.y + gun.y, gvp.y - gvn.y,
                       tup.y + 2.f * tuc.y + tun.y, tvp.y - tvn.y);
        acc += pixdiff(gup.z + 2.f * guc.z + gun.z, gvp.z - gvn.z,
                       tup.z + 2.f * tuc.z + tun.z, tvp.z - tvn.z);
        acc += pixdiff(gup.w + 2.f * guc.w + gun.w, gvp.w - gvn.w,
                       tup.w + 2.f * tuc.w + tun.w, tvp.w - tvn.w);

        gup = guc; guc = gun; gvp = gvc; gvc = gvn;
        tup = tuc; tuc = tun; tvp = tvc; tvc = tvn;
        rg = fg; rhg = fhg; rt = ft; rht = fht;
        fg = ng; fhg = nhg; ft = nt_; fht = nht;
    }

    // wave butterfly + block reduce, one partial per block (no global atomics)
    #pragma unroll
    for (int o = 32; o; o >>= 1) acc += __shfl_xor(acc, o, 64);
    __shared__ float wsum[NT / 64];
    if (lane == 0) wsum[wave] = acc;
    __syncthreads();
    if (t == 0) {
        float s = 0.f;
        #pragma unroll
        for (int w = 0; w < NT / 64; ++w) s += wsum[w];
        partial[blockIdx.y * gridDim.x + blockIdx.x] = s;
    }
}

__global__ __launch_bounds__(256)
void hnl_reduce(const float* __restrict__ partial, float* __restrict__ out,
                int n, float scale) {
    const int t = threadIdx.x;
    float s = 0.f;
    for (int i = t; i < n; i += 256) s += partial[i];
    #pragma unroll
    for (int o = 32; o; o >>= 1) s += __shfl_xor(s, o, 64);
    __shared__ float wsum[4];
    if ((t & 63) == 0) wsum[t >> 6] = s;
    __syncthreads();
    if (t == 0) out[0] = (wsum[0] + wsum[1] + wsum[2] + wsum[3]) * scale;
}

extern "C" void kernel_launch(void* const* d_in, const int* in_sizes, int n_in,
                              void* d_out, int out_size, void* d_ws, size_t ws_size,
                              hipStream_t stream) {
    const float* gen = (const float*)d_in[0];
    const float* tgt = (const float*)d_in[1];
    float* out = (float*)d_out;
    float* ws  = (float*)d_ws;

    const int B = in_sizes[0] / (IMG_H * IMG_W);     // 32
    const int nBands = IMG_H / BAND;                 // 32
    const int nPartials = B * nBands;                // 1024
    const float scale = 1.f / ((float)B * 3.f * IMG_H * IMG_W);

    dim3 grid(nBands, B);                            // (32, 32) = 1024 blocks
    hnl_main<<<grid, NT, 0, stream>>>(gen, tgt, ws);
    hnl_reduce<<<1, 256, 0, stream>>>(ws, out, nPartials, scale);
}